// Round 13
// baseline (214.255 us; speedup 1.0000x reference)
//
#include <hip/hip_runtime.h>

#define H 128
#define W 128
#define HW 16384
#define CIN 128
#define COUT 64
#define BATCH 4
#define EPS 1e-5f
#define PY 130   // padded y extent
#define PX 132   // padded x extent

// ---- ws layout (float offsets) ----
// fb / xnb: bf16 [B][PY][PX][128] channels-last (fb pads zeroed; xnb pads unused/masked)
#define FB_OFF    0                    // 8785920 bf16 = 4392960 f32
#define XNB_OFF   4392960              // 8785920 bf16 = 4392960 f32
#define KPART_OFF XNB_OFF              // f32 [4][B][9][HW] TRANSIENT (consumed by expk before pac writes xnb)
#define KERN_OFF  (XNB_OFF + 4392960)  // 8785920: f32 [B][9][HW] = 589824
#define WT_OFF    (KERN_OFF + 589824)  // 9375744: bf16 [9][128][128] = 73728 f32
#define CT_OFF    (WT_OFF + 73728)     // 9449472: bf16 [9][64][128]  = 36864 f32
#define STATS_OFF (CT_OFF + 36864)     // 9486336
#define SUM1   (STATS_OFF)
#define SUMSQ1 (STATS_OFF + 512)
#define SUM2   (STATS_OFF + 1024)
#define SUMSQ2 (STATS_OFF + 1280)
#define SCALE1 (STATS_OFF + 1536)
#define SHIFT1 (STATS_OFF + 2048)
#define SCALE2 (STATS_OFF + 2560)
#define SHIFT2 (STATS_OFF + 2816)
// total 9489408 f32 = 38.0 MB

typedef float f32x4 __attribute__((ext_vector_type(4)));
typedef short bf16x8 __attribute__((ext_vector_type(8)));
typedef short bf16x4 __attribute__((ext_vector_type(4)));
#define MFMA16 __builtin_amdgcn_mfma_f32_16x16x32_bf16

__device__ __forceinline__ unsigned short f2b(float f) {
  union { float f; unsigned u; } un; un.f = f;
  unsigned r = un.u + 0x7FFF + ((un.u >> 16) & 1);   // RNE
  return (unsigned short)(r >> 16);
}
__device__ __forceinline__ float b2f(unsigned short u) {
  union { unsigned u; float f; } x; x.u = ((unsigned)u) << 16; return x.f;
}
__device__ __forceinline__ void load_lds16(const void* g, void* l) {
  __builtin_amdgcn_global_load_lds(
      (const __attribute__((address_space(1))) unsigned int*)g,
      (__attribute__((address_space(3))) unsigned int*)l, 16, 0, 0);
}

// XCD-chunked bijective swizzle for nwg=1024 (8 XCDs, 128 wgs per XCD chunk)
__device__ __forceinline__ void decode_wg(int bid, int& b, int& y, int& x0) {
  int wgid = (bid & 7) * 128 + (bid >> 3);
  b = wgid >> 8;
  int rem = wgid & 255;
  y = rem >> 1;
  x0 = (rem & 1) << 6;
}

// ---------------------------------------------------------------------------
// zero pads of fb (pac stages fb via DMA, pads must be true zero)
// ---------------------------------------------------------------------------
__global__ __launch_bounds__(256) void zero_pads(float* __restrict__ ws) {
  int id = blockIdx.x * 256 + threadIdx.x;
  if (id >= 4 * 776 * 16) return;
  int chunk = id & 15; int rest = id >> 4;
  int px = rest % 776; int b = rest / 776;
  int row, xx;
  if (px < 264) { row = (px < 132) ? 0 : 129; xx = px % 132; }
  else { int q = px - 264; row = 1 + (q >> 2); int m = q & 3; xx = m ? 128 + m : 0; }
  unsigned short* base = (unsigned short*)(ws + FB_OFF);
  bf16x8 z = {0, 0, 0, 0, 0, 0, 0, 0};
  *(bf16x8*)(base + ((b * PY + row) * PX + xx) * 128 + chunk * 8) = z;
}

// ---------------------------------------------------------------------------
// transpose feat [b][c][y][x] f32 -> fb [b][y+1][x+1][c] bf16 (channels-last)
// ---------------------------------------------------------------------------
__global__ __launch_bounds__(256) void transpose_feat(const float* __restrict__ feat,
                                                      float* __restrict__ ws) {
  __shared__ __align__(16) char T[128 * 256];   // 32 KB
  int b = blockIdx.x >> 7, y = blockIdx.x & 127;
  int t = threadIdx.x;
  int x = t & 127, ch = t >> 7;
  const float* fp = feat + ((b * CIN) << 14) + (y << 7) + x;
#pragma unroll 8
  for (int cc = 0; cc < 64; ++cc) {
    int c = ch * 64 + cc;
    float v = fp[c << 14];
    int byte = (x << 8) + (c << 1);
    byte ^= (x & 7) << 4;
    *(unsigned short*)(T + byte) = f2b(v);
  }
  __syncthreads();
  unsigned short* fb = (unsigned short*)(ws + FB_OFF);
#pragma unroll
  for (int it = 0; it < 8; ++it) {
    int flat = it * 256 + t;
    int px = flat >> 4, j = flat & 15;
    int byte = (px << 8) + (j << 4);
    byte ^= (px & 7) << 4;
    bf16x8 v = *(bf16x8*)(T + byte);
    *(bf16x8*)(fb + ((b * PY + y + 1) * PX + px + 1) * 128 + j * 8) = v;
  }
}

// ---------------------------------------------------------------------------
// kern partials: kpart[cs][b][k][pix] = sum_{c in chunk cs} (g_k - g0)^2
// ---------------------------------------------------------------------------
__global__ __launch_bounds__(256) void kern_part(const float* __restrict__ guide,
                                                 float* __restrict__ ws) {
  int p = blockIdx.x * 256 + threadIdx.x;
  int cs = blockIdx.y;
  int b = p >> 14;
  int pix = p & (HW - 1);
  int y = pix >> 7, x = pix & (W - 1);
  float acc[9];
#pragma unroll
  for (int k = 0; k < 9; ++k) acc[k] = 0.f;
  const float* gb = guide + ((b * CIN + cs * 32) << 14);
  for (int c = 0; c < 32; ++c) {
    const float* gc = gb + (c << 14);
    float g0 = gc[pix];
#pragma unroll
    for (int dy = -1; dy <= 1; ++dy) {
#pragma unroll
      for (int dx = -1; dx <= 1; ++dx) {
        int yy = y + dy, xx = x + dx;
        bool ok = ((unsigned)yy < (unsigned)H) && ((unsigned)xx < (unsigned)W);
        int yc = min(max(yy, 0), H - 1);
        int xc = min(max(xx, 0), W - 1);
        float g = gc[yc * W + xc];
        g = ok ? g : 0.f;
        float d = g - g0;
        acc[(dy + 1) * 3 + (dx + 1)] += d * d;
      }
    }
  }
  float* kp = ws + KPART_OFF;
#pragma unroll
  for (int k = 0; k < 9; ++k)
    kp[(((cs * BATCH + b) * 9 + k) << 14) + pix] = acc[k];
}

// kern = exp(-0.5 * sum_cs kpart)
__global__ __launch_bounds__(256) void expk(float* __restrict__ ws) {
  int i = blockIdx.x * 256 + threadIdx.x;   // float4 index, 147456 total
  const float4* kp = reinterpret_cast<const float4*>(ws + KPART_OFF);
  float4 a = kp[i], b = kp[i + 147456], c = kp[i + 2 * 147456], d = kp[i + 3 * 147456];
  float4 o;
  o.x = __expf(-0.5f * (a.x + b.x + c.x + d.x));
  o.y = __expf(-0.5f * (a.y + b.y + c.y + d.y));
  o.z = __expf(-0.5f * (a.z + b.z + c.z + d.z));
  o.w = __expf(-0.5f * (a.w + b.w + c.w + d.w));
  reinterpret_cast<float4*>(ws + KERN_OFF)[i] = o;
}

// ---------------------------------------------------------------------------
// weight transform: Wt[k][o][c] = bf16(pac_w[o][c][k]); Ct likewise for conv_w
// ---------------------------------------------------------------------------
__global__ __launch_bounds__(256) void prep_w(const float* __restrict__ pw,
                                              const float* __restrict__ cw,
                                              float* __restrict__ ws) {
  int t = blockIdx.x * 256 + threadIdx.x;
  unsigned short* Wtu = (unsigned short*)(ws + WT_OFF);
  unsigned short* Ctu = (unsigned short*)(ws + CT_OFF);
  if (t < 147456) {
    int k = t >> 14, rem = t & 16383, o = rem >> 7, c = rem & 127;
    Wtu[t] = f2b(pw[(o * CIN + c) * 9 + k]);
  } else {
    int u = t - 147456;
    int k = u >> 13, rem = u & 8191, o = rem >> 7, c = rem & 127;
    Ctu[u] = f2b(cw[(o * CIN + c) * 9 + k]);
  }
}

// ---------------------------------------------------------------------------
// pac tile stage (DMA, 512-thread version): [3][66][128] bf16, linear LDS,
// src pre-swizzled. 8 waves x 6 gload_lds; halo px 0,65 reg-staged (t<96).
// ---------------------------------------------------------------------------
__device__ __forceinline__ void stage_tile(const unsigned short* __restrict__ src_base,
                                           char* Fs, int b, int y, int x0, int t) {
  int lane = t & 63, w = t >> 6;
  int j = lane & 15, pl = lane >> 4;
#pragma unroll
  for (int q = 0; q < 6; ++q) {
    int m = w * 6 + q;
    int r = m >> 4, pblk = m & 15;
    int p = 1 + pblk * 4 + pl;
    int jx = (j & 8) | ((j & 7) ^ (p & 7));
    const unsigned short* src = src_base + (((b * PY + y + r) * PX + x0 + p) << 7) + jx * 8;
    char* dst = Fs + ((r * 66 + 1 + pblk * 4) << 8);
    load_lds16(src, dst);
  }
  if (t < 96) {
    int r = t >> 5, side = (t >> 4) & 1, jj = t & 15;
    int p = side ? 65 : 0;
    int jx = (jj & 8) | ((jj & 7) ^ (p & 7));
    const unsigned short* src = src_base + (((b * PY + y + r) * PX + x0 + p) << 7) + jx * 8;
    bf16x8 v = *(const bf16x8*)src;
    *(bf16x8*)(Fs + ((r * 66 + p) << 8) + jj * 16) = v;
  }
}

// ---------------------------------------------------------------------------
// conv tile stage (REGISTER path, fused IN1+ReLU+pad-mask, 512-thread ver.)
// ---------------------------------------------------------------------------
__device__ __forceinline__ void stage_fused(const unsigned short* __restrict__ src_base,
                                            char* Fs, const float* __restrict__ sc,
                                            const float* __restrict__ sh,
                                            int b, int y, int x0, int t) {
  int lane = t & 63, w = t >> 6;
  int j = lane & 15, pl = lane >> 4;
#pragma unroll
  for (int q = 0; q < 6; ++q) {
    int m = w * 6 + q;
    int r = m >> 4, pblk = m & 15;
    int p = 1 + pblk * 4 + pl;
    int jx = (j & 8) | ((j & 7) ^ (p & 7));
    int yy = y + r, xx = x0 + p;
    bf16x8 v = *(const bf16x8*)(src_base + (((b * PY + yy) * PX + xx) << 7) + jx * 8);
    bool pad = (yy == 0) | (yy == PY - 1) | (xx == 0) | (xx >= PX - 3);
    f32x4 s0 = *(const f32x4*)(sc + jx * 8), s1 = *(const f32x4*)(sc + jx * 8 + 4);
    f32x4 h0 = *(const f32x4*)(sh + jx * 8), h1 = *(const f32x4*)(sh + jx * 8 + 4);
    bf16x8 o;
#pragma unroll
    for (int e = 0; e < 4; ++e) {
      float a0 = fmaxf(fmaf(b2f((unsigned short)v[e]), s0[e], h0[e]), 0.f);
      float a1 = fmaxf(fmaf(b2f((unsigned short)v[e + 4]), s1[e], h1[e]), 0.f);
      o[e] = (short)f2b(pad ? 0.f : a0);
      o[e + 4] = (short)f2b(pad ? 0.f : a1);
    }
    *(bf16x8*)(Fs + ((r * 66 + p) << 8) + j * 16) = o;
  }
  if (t < 96) {
    int r = t >> 5, side = (t >> 4) & 1, jj = t & 15;
    int p = side ? 65 : 0;
    int jx = (jj & 8) | ((jj & 7) ^ (p & 7));
    int yy = y + r, xx = x0 + p;
    bf16x8 v = *(const bf16x8*)(src_base + (((b * PY + yy) * PX + xx) << 7) + jx * 8);
    bool pad = (yy == 0) | (yy == PY - 1) | (xx == 0) | (xx >= PX - 3);
    f32x4 s0 = *(const f32x4*)(sc + jx * 8), s1 = *(const f32x4*)(sc + jx * 8 + 4);
    f32x4 h0 = *(const f32x4*)(sh + jx * 8), h1 = *(const f32x4*)(sh + jx * 8 + 4);
    bf16x8 o;
#pragma unroll
    for (int e = 0; e < 4; ++e) {
      float a0 = fmaxf(fmaf(b2f((unsigned short)v[e]), s0[e], h0[e]), 0.f);
      float a1 = fmaxf(fmaf(b2f((unsigned short)v[e + 4]), s1[e], h1[e]), 0.f);
      o[e] = (short)f2b(pad ? 0.f : a0);
      o[e + 4] = (short)f2b(pad ? 0.f : a1);
    }
    *(bf16x8*)(Fs + ((r * 66 + p) << 8) + jj * 16) = o;
  }
}

// ---------------------------------------------------------------------------
// pac via MFMA, 8-WAVE blocks (512 thr), 8-way o-split (16 o per wave).
// Same tile, same grid, same per-block traffic as r12 -> 2x resident waves.
// Per wave: 36 A-loads (3-buf 2-tap ring), 144 MFMA, 144 LDS b128.
// ---------------------------------------------------------------------------
__global__ __launch_bounds__(512, 4) void pac_mfma(float* __restrict__ ws) {
  __shared__ __align__(16) char Fs[3 * 66 * 256];   // 50688 B
  int b, y, x0;
  decode_wg(blockIdx.x, b, y, x0);
  const int t = threadIdx.x;
  const unsigned short* Wtu = (const unsigned short*)(ws + WT_OFF);
  const unsigned short* fb = (const unsigned short*)(ws + FB_OFF);
  unsigned short* xnb = (unsigned short*)(ws + XNB_OFF);
  const int lane = t & 63, l15 = lane & 15, lg = lane >> 4;
  const int o0 = (t >> 6) * 16;   // 8 waves x 16 o

  const unsigned short* Wbase = Wtu + (o0 + l15) * 128 + lg * 8;   // +k*16384 +ks*32
  const float* kernb = ws + KERN_OFF + ((b * 9) << 14) + (y << 7) + x0 + l15;

  // rings: wa[buf][ks], kr[buf][pt]; prefetch distance 2 taps
  bf16x8 wa[3][4];
  float kr[3][4];
#pragma unroll
  for (int pk = 0; pk < 2; ++pk) {
#pragma unroll
    for (int ks = 0; ks < 4; ++ks)
      wa[pk][ks] = *(const bf16x8*)(Wbase + pk * 16384 + ks * 32);
#pragma unroll
    for (int pt = 0; pt < 4; ++pt) kr[pk][pt] = kernb[(pk << 14) + pt * 16];
  }

  stage_tile(fb, Fs, b, y, x0, t);
  __syncthreads();

  const f32x4 vzero = {0.f, 0.f, 0.f, 0.f};
  f32x4 pacc[4];
#pragma unroll
  for (int pt = 0; pt < 4; ++pt) pacc[pt] = vzero;

#pragma unroll
  for (int k = 0; k < 9; ++k) {
    const int dy = k / 3, dxi = k % 3;        // compile-time under full unroll
    const int cur = k % 3;
    if (k + 2 <= 8) {                          // prefetch tap k+2
      const int nb = (k + 2) % 3;
#pragma unroll
      for (int ks = 0; ks < 4; ++ks)
        wa[nb][ks] = *(const bf16x8*)(Wbase + (k + 2) * 16384 + ks * 32);
#pragma unroll
      for (int pt = 0; pt < 4; ++pt) kr[nb][pt] = kernb[((k + 2) << 14) + pt * 16];
    }
    f32x4 z[4];
#pragma unroll
    for (int ks = 0; ks < 4; ++ks) {
#pragma unroll
      for (int pt = 0; pt < 4; ++pt) {
        int p = dxi + pt * 16 + l15;
        int byte = ((dy * 66 + p) << 8) + ks * 64 + lg * 16;
        byte ^= (p & 7) << 4;
        bf16x8 bv = *(const bf16x8*)(Fs + byte);
        z[pt] = MFMA16(wa[cur][ks], bv, ks ? z[pt] : vzero, 0, 0, 0);
      }
    }
#pragma unroll
    for (int pt = 0; pt < 4; ++pt) {
      float kvv = kr[cur][pt];
#pragma unroll
      for (int i = 0; i < 4; ++i)
        pacc[pt][i] = fmaf(kvv, z[pt][i], pacc[pt][i]);
    }
  }

  // write raw bf16 pac (padded c-last) + stats
  float* sum1 = ws + SUM1;
  float* sumsq1 = ws + SUMSQ1;
#pragma unroll
  for (int pt = 0; pt < 4; ++pt) {
    int px = x0 + pt * 16 + l15;
    int base = ((b * PY + y + 1) * PX + px + 1) * 128;
    bf16x4 vA;
#pragma unroll
    for (int i = 0; i < 4; ++i) vA[i] = (short)f2b(pacc[pt][i]);
    *(bf16x4*)(xnb + base + o0 + lg * 4) = vA;
  }
#pragma unroll
  for (int i = 0; i < 4; ++i) {
    float s = 0.f, sq = 0.f;
#pragma unroll
    for (int pt = 0; pt < 4; ++pt) {
      float v = pacc[pt][i];
      s += v; sq += v * v;
    }
#pragma unroll
    for (int m = 1; m < 16; m <<= 1) {
      s += __shfl_xor(s, m);
      sq += __shfl_xor(sq, m);
    }
    if (l15 == 0) {
      int o = o0 + lg * 4 + i;
      atomicAdd(&sum1[b * CIN + o], s);
      atomicAdd(&sumsq1[b * CIN + o], sq);
    }
  }
}

// ---------------------------------------------------------------------------
// per-(b,c) stats -> scale = rsqrt(var+eps), shift = -mu*scale
// ---------------------------------------------------------------------------
__global__ void stats_kernel(float* __restrict__ ws, int sumoff, int sqoff,
                             int scoff, int shoff, int n, float invN) {
  int i = blockIdx.x * blockDim.x + threadIdx.x;
  if (i >= n) return;
  float mu = ws[sumoff + i] * invN;
  float var = ws[sqoff + i] * invN - mu * mu;
  var = fmaxf(var, 0.f);
  float rs = rsqrtf(var + EPS);
  ws[scoff + i] = rs;
  ws[shoff + i] = -mu * rs;
}

// ---------------------------------------------------------------------------
// decode conv via MFMA, 8-WAVE blocks: 4-way o-split x 2-way px-split.
// Staging fused with IN1+ReLU (register path). Per wave: 36 A-loads,
// 72 MFMA, 72 LDS b128.
// ---------------------------------------------------------------------------
__global__ __launch_bounds__(512, 4) void conv_mfma(float* __restrict__ ws,
                                                    float* __restrict__ out) {
  __shared__ __align__(16) char Xs[3 * 66 * 256];
  int b, y, x0;
  decode_wg(blockIdx.x, b, y, x0);
  const int t = threadIdx.x;
  const unsigned short* Ctu = (const unsigned short*)(ws + CT_OFF);
  const unsigned short* xnb = (const unsigned short*)(ws + XNB_OFF);
  const float* sc1 = ws + SCALE1 + b * CIN;
  const float* sh1 = ws + SHIFT1 + b * CIN;
  const int lane = t & 63, l15 = lane & 15, lg = lane >> 4;
  const int wq = t >> 6;
  const int o0 = (wq & 3) * 16;   // 4 o-groups
  const int ph = wq >> 2;         // px half: pt in {ph*2, ph*2+1}

  const unsigned short* Cbase = Ctu + (o0 + l15) * 128 + lg * 8;   // +k*8192 +ks*32

  bf16x8 wa[3][4];
#pragma unroll
  for (int pk = 0; pk < 2; ++pk)
#pragma unroll
    for (int ks = 0; ks < 4; ++ks)
      wa[pk][ks] = *(const bf16x8*)(Cbase + pk * 8192 + ks * 32);

  stage_fused(xnb, Xs, sc1, sh1, b, y, x0, t);
  __syncthreads();

  const f32x4 vzero = {0.f, 0.f, 0.f, 0.f};
  f32x4 acc[2];
  acc[0] = vzero; acc[1] = vzero;

#pragma unroll
  for (int k = 0; k < 9; ++k) {
    const int dy = k / 3, dxi = k % 3;
    const int cur = k % 3;
    if (k + 2 <= 8) {
      const int nb = (k + 2) % 3;
#pragma unroll
      for (int ks = 0; ks < 4; ++ks)
        wa[nb][ks] = *(const bf16x8*)(Cbase + (k + 2) * 8192 + ks * 32);
    }
#pragma unroll
    for (int ks = 0; ks < 4; ++ks) {
#pragma unroll
      for (int pq = 0; pq < 2; ++pq) {
        int pt = ph * 2 + pq;
        int p = dxi + pt * 16 + l15;
        int byte = ((dy * 66 + p) << 8) + ks * 64 + lg * 16;
        byte ^= (p & 7) << 4;
        bf16x8 bv = *(const bf16x8*)(Xs + byte);
        acc[pq] = MFMA16(wa[cur][ks], bv, acc[pq], 0, 0, 0);
      }
    }
  }

  float* sum2 = ws + SUM2;
  float* sumsq2 = ws + SUMSQ2;
#pragma unroll
  for (int pq = 0; pq < 2; ++pq) {
#pragma unroll
    for (int i = 0; i < 4; ++i) {
      int o = o0 + lg * 4 + i;
      int px = x0 + (ph * 2 + pq) * 16 + l15;
      out[((b * COUT + o) << 14) + (y << 7) + px] = acc[pq][i];
    }
  }
#pragma unroll
  for (int i = 0; i < 4; ++i) {
    float s = 0.f, sq = 0.f;
#pragma unroll
    for (int pq = 0; pq < 2; ++pq) { float v = acc[pq][i]; s += v; sq += v * v; }
#pragma unroll
    for (int m = 1; m < 16; m <<= 1) {
      s += __shfl_xor(s, m);
      sq += __shfl_xor(sq, m);
    }
    if (l15 == 0) {
      int o = o0 + lg * 4 + i;
      atomicAdd(&sum2[b * COUT + o], s);
      atomicAdd(&sumsq2[b * COUT + o], sq);
    }
  }
}

// ---------------------------------------------------------------------------
// final InstanceNorm + ReLU on d_out (float4)
// ---------------------------------------------------------------------------
__global__ __launch_bounds__(256) void norm_kernel(float* __restrict__ out,
                                                   const float* __restrict__ ws) {
  int i = blockIdx.x * 256 + threadIdx.x;
  int bc = (i * 4) >> 14;
  float sc = ws[SCALE2 + bc];
  float sh = ws[SHIFT2 + bc];
  float4 v = reinterpret_cast<float4*>(out)[i];
  v.x = fmaxf(fmaf(v.x, sc, sh), 0.f);
  v.y = fmaxf(fmaf(v.y, sc, sh), 0.f);
  v.z = fmaxf(fmaf(v.z, sc, sh), 0.f);
  v.w = fmaxf(fmaf(v.w, sc, sh), 0.f);
  reinterpret_cast<float4*>(out)[i] = v;
}

extern "C" void kernel_launch(void* const* d_in, const int* in_sizes, int n_in,
                              void* d_out, int out_size, void* d_ws, size_t ws_size,
                              hipStream_t stream) {
  const float* feat = (const float*)d_in[0];
  const float* guide = (const float*)d_in[1];
  const float* pac_w = (const float*)d_in[2];
  const float* conv_w = (const float*)d_in[4];
  float* ws = (float*)d_ws;
  float* out = (float*)d_out;

  hipMemsetAsync(ws + STATS_OFF, 0, 1536 * sizeof(float), stream);

  prep_w<<<dim3(864), 256, 0, stream>>>(pac_w, conv_w, ws);
  zero_pads<<<dim3(194), 256, 0, stream>>>(ws);              // fb pads only
  transpose_feat<<<dim3(512), 256, 0, stream>>>(feat, ws);
  kern_part<<<dim3(256, 4), 256, 0, stream>>>(guide, ws);    // writes KPART (aliases xnb)
  expk<<<dim3(576), 256, 0, stream>>>(ws);                   // consumes KPART -> kern
  pac_mfma<<<dim3(1024), 512, 0, stream>>>(ws);
  stats_kernel<<<dim3(2), 256, 0, stream>>>(ws, SUM1, SUMSQ1, SCALE1, SHIFT1,
                                            BATCH * CIN, 1.f / HW);
  conv_mfma<<<dim3(1024), 512, 0, stream>>>(ws, out);        // IN1+ReLU fused in stage
  stats_kernel<<<dim3(1), 256, 0, stream>>>(ws, SUM2, SUMSQ2, SCALE2, SHIFT2,
                                            BATCH * COUT, 1.f / HW);
  norm_kernel<<<dim3(BATCH * COUT * HW / 1024), 256, 0, stream>>>(out, ws);
}

// Round 14
// 157.406 us; speedup vs baseline: 1.3612x; 1.3612x over previous
//
#include <hip/hip_runtime.h>

#define H 128
#define W 128
#define HW 16384
#define CIN 128
#define COUT 64
#define BATCH 4
#define EPS 1e-5f
#define PY 130   // padded y extent
#define PX 132   // padded x extent

// ---- ws layout (float offsets) ----
// fb / xnb: bf16 [B][PY][PX][128] channels-last (fb pads zeroed; xnb pads unused/masked)
#define FB_OFF    0                    // 8785920 bf16 = 4392960 f32
#define XNB_OFF   4392960              // 8785920 bf16 = 4392960 f32
#define KPART_OFF XNB_OFF              // f32 [4][B][9][HW] TRANSIENT (consumed by expk before pac writes xnb)
#define KERN_OFF  (XNB_OFF + 4392960)  // 8785920: f32 [B][9][HW] = 589824
#define WT_OFF    (KERN_OFF + 589824)  // 9375744: bf16 [9][128][128] = 73728 f32
#define CT_OFF    (WT_OFF + 73728)     // 9449472: bf16 [9][64][128]  = 36864 f32
#define STATS_OFF (CT_OFF + 36864)     // 9486336
#define SUM1   (STATS_OFF)
#define SUMSQ1 (STATS_OFF + 512)
#define SUM2   (STATS_OFF + 1024)
#define SUMSQ2 (STATS_OFF + 1280)
#define SCALE1 (STATS_OFF + 1536)
#define SHIFT1 (STATS_OFF + 2048)
#define SCALE2 (STATS_OFF + 2560)
#define SHIFT2 (STATS_OFF + 2816)
// total 9489408 f32 = 38.0 MB

typedef float f32x4 __attribute__((ext_vector_type(4)));
typedef short bf16x8 __attribute__((ext_vector_type(8)));
typedef short bf16x4 __attribute__((ext_vector_type(4)));
#define MFMA16 __builtin_amdgcn_mfma_f32_16x16x32_bf16

__device__ __forceinline__ unsigned short f2b(float f) {
  union { float f; unsigned u; } un; un.f = f;
  unsigned r = un.u + 0x7FFF + ((un.u >> 16) & 1);   // RNE
  return (unsigned short)(r >> 16);
}
__device__ __forceinline__ float b2f(unsigned short u) {
  union { unsigned u; float f; } x; x.u = ((unsigned)u) << 16; return x.f;
}
__device__ __forceinline__ void load_lds16(const void* g, void* l) {
  __builtin_amdgcn_global_load_lds(
      (const __attribute__((address_space(1))) unsigned int*)g,
      (__attribute__((address_space(3))) unsigned int*)l, 16, 0, 0);
}

// XCD-chunked bijective swizzle for nwg=1024 (8 XCDs, 128 wgs per XCD chunk)
__device__ __forceinline__ void decode_wg(int bid, int& b, int& y, int& x0) {
  int wgid = (bid & 7) * 128 + (bid >> 3);
  b = wgid >> 8;
  int rem = wgid & 255;
  y = rem >> 1;
  x0 = (rem & 1) << 6;
}

// ---------------------------------------------------------------------------
// prep_all: ONE dispatch for 4 independent preprocessing jobs:
//   blocks [0,512):      transpose feat -> fb (channels-last bf16)
//   blocks [512,706):    zero fb pads
//   blocks [706,1570):   weight transform Wt / Ct
//   blocks [1570,2594):  kern partials kpart[cs][b][k][pix]
// ---------------------------------------------------------------------------
__global__ __launch_bounds__(256) void prep_all(const float* __restrict__ feat,
                                                const float* __restrict__ guide,
                                                const float* __restrict__ pw,
                                                const float* __restrict__ cw,
                                                float* __restrict__ ws) {
  __shared__ __align__(16) char T[128 * 256];   // used by transpose branch only
  const int bid = blockIdx.x;
  const int t = threadIdx.x;

  if (bid < 512) {
    // ---- transpose feat [b][c][y][x] f32 -> fb [b][y+1][x+1][c] bf16 ----
    int b = bid >> 7, y = bid & 127;
    int x = t & 127, ch = t >> 7;
    const float* fp = feat + ((b * CIN) << 14) + (y << 7) + x;
#pragma unroll 8
    for (int cc = 0; cc < 64; ++cc) {
      int c = ch * 64 + cc;
      float v = fp[c << 14];
      int byte = (x << 8) + (c << 1);
      byte ^= (x & 7) << 4;
      *(unsigned short*)(T + byte) = f2b(v);
    }
    __syncthreads();
    unsigned short* fb = (unsigned short*)(ws + FB_OFF);
#pragma unroll
    for (int it = 0; it < 8; ++it) {
      int flat = it * 256 + t;
      int px = flat >> 4, j = flat & 15;
      int byte = (px << 8) + (j << 4);
      byte ^= (px & 7) << 4;
      bf16x8 v = *(bf16x8*)(T + byte);
      *(bf16x8*)(fb + ((b * PY + y + 1) * PX + px + 1) * 128 + j * 8) = v;
    }
  } else if (bid < 706) {
    // ---- zero fb pads ----
    int id = (bid - 512) * 256 + t;
    if (id < 4 * 776 * 16) {
      int chunk = id & 15; int rest = id >> 4;
      int px = rest % 776; int b = rest / 776;
      int row, xx;
      if (px < 264) { row = (px < 132) ? 0 : 129; xx = px % 132; }
      else { int q = px - 264; row = 1 + (q >> 2); int m = q & 3; xx = m ? 128 + m : 0; }
      unsigned short* base = (unsigned short*)(ws + FB_OFF);
      bf16x8 z = {0, 0, 0, 0, 0, 0, 0, 0};
      *(bf16x8*)(base + ((b * PY + row) * PX + xx) * 128 + chunk * 8) = z;
    }
  } else if (bid < 1570) {
    // ---- weight transform ----
    int tg = (bid - 706) * 256 + t;
    unsigned short* Wtu = (unsigned short*)(ws + WT_OFF);
    unsigned short* Ctu = (unsigned short*)(ws + CT_OFF);
    if (tg < 147456) {
      int k = tg >> 14, rem = tg & 16383, o = rem >> 7, c = rem & 127;
      Wtu[tg] = f2b(pw[(o * CIN + c) * 9 + k]);
    } else {
      int u = tg - 147456;
      int k = u >> 13, rem = u & 8191, o = rem >> 7, c = rem & 127;
      Ctu[u] = f2b(cw[(o * CIN + c) * 9 + k]);
    }
  } else {
    // ---- kern partials: kpart[cs][b][k][pix] (c-loop unrolled 4x for MLP) ----
    int rel = bid - 1570;                  // 0..1023
    int cs = rel >> 8;
    int p = (rel & 255) * 256 + t;
    int b = p >> 14;
    int pix = p & (HW - 1);
    int y = pix >> 7, x = pix & (W - 1);
    float acc[9];
#pragma unroll
    for (int k = 0; k < 9; ++k) acc[k] = 0.f;
    const float* gb = guide + ((b * CIN + cs * 32) << 14);
#pragma unroll 4
    for (int c = 0; c < 32; ++c) {
      const float* gc = gb + (c << 14);
      float g0 = gc[pix];
#pragma unroll
      for (int dy = -1; dy <= 1; ++dy) {
#pragma unroll
        for (int dx = -1; dx <= 1; ++dx) {
          int yy = y + dy, xx = x + dx;
          bool ok = ((unsigned)yy < (unsigned)H) && ((unsigned)xx < (unsigned)W);
          int yc = min(max(yy, 0), H - 1);
          int xc = min(max(xx, 0), W - 1);
          float g = gc[yc * W + xc];
          g = ok ? g : 0.f;
          float d = g - g0;
          acc[(dy + 1) * 3 + (dx + 1)] += d * d;
        }
      }
    }
    float* kp = ws + KPART_OFF;
#pragma unroll
    for (int k = 0; k < 9; ++k)
      kp[(((cs * BATCH + b) * 9 + k) << 14) + pix] = acc[k];
  }
}

// kern = exp(-0.5 * sum_cs kpart)
__global__ __launch_bounds__(256) void expk(float* __restrict__ ws) {
  int i = blockIdx.x * 256 + threadIdx.x;   // float4 index, 147456 total
  const float4* kp = reinterpret_cast<const float4*>(ws + KPART_OFF);
  float4 a = kp[i], b = kp[i + 147456], c = kp[i + 2 * 147456], d = kp[i + 3 * 147456];
  float4 o;
  o.x = __expf(-0.5f * (a.x + b.x + c.x + d.x));
  o.y = __expf(-0.5f * (a.y + b.y + c.y + d.y));
  o.z = __expf(-0.5f * (a.z + b.z + c.z + d.z));
  o.w = __expf(-0.5f * (a.w + b.w + c.w + d.w));
  reinterpret_cast<float4*>(ws + KERN_OFF)[i] = o;
}

// ---------------------------------------------------------------------------
// pac tile stage (DMA): [3 rows][66 px][128 c] bf16, linear LDS, src pre-swizzled
// ---------------------------------------------------------------------------
__device__ __forceinline__ void stage_tile(const unsigned short* __restrict__ src_base,
                                           char* Fs, int b, int y, int x0, int t) {
  int lane = t & 63, w = t >> 6;
  int j = lane & 15, pl = lane >> 4;
#pragma unroll
  for (int q = 0; q < 12; ++q) {
    int m = w * 12 + q;
    int r = m >> 4, pblk = m & 15;
    int p = 1 + pblk * 4 + pl;
    int jx = (j & 8) | ((j & 7) ^ (p & 7));
    const unsigned short* src = src_base + (((b * PY + y + r) * PX + x0 + p) << 7) + jx * 8;
    char* dst = Fs + ((r * 66 + 1 + pblk * 4) << 8);
    load_lds16(src, dst);
  }
  if (t < 96) {
    int r = t >> 5, side = (t >> 4) & 1, jj = t & 15;
    int p = side ? 65 : 0;
    int jx = (jj & 8) | ((jj & 7) ^ (p & 7));
    const unsigned short* src = src_base + (((b * PY + y + r) * PX + x0 + p) << 7) + jx * 8;
    bf16x8 v = *(const bf16x8*)src;
    *(bf16x8*)(Fs + ((r * 66 + p) << 8) + jj * 16) = v;
  }
}

// ---------------------------------------------------------------------------
// conv tile stage (REGISTER path, fused IN1+ReLU+pad-mask)
// ---------------------------------------------------------------------------
__device__ __forceinline__ void stage_fused(const unsigned short* __restrict__ src_base,
                                            char* Fs, const float* __restrict__ sc,
                                            const float* __restrict__ sh,
                                            int b, int y, int x0, int t) {
  int lane = t & 63, w = t >> 6;
  int j = lane & 15, pl = lane >> 4;
#pragma unroll
  for (int q = 0; q < 12; ++q) {
    int m = w * 12 + q;
    int r = m >> 4, pblk = m & 15;
    int p = 1 + pblk * 4 + pl;
    int jx = (j & 8) | ((j & 7) ^ (p & 7));
    int yy = y + r, xx = x0 + p;
    bf16x8 v = *(const bf16x8*)(src_base + (((b * PY + yy) * PX + xx) << 7) + jx * 8);
    bool pad = (yy == 0) | (yy == PY - 1) | (xx == 0) | (xx >= PX - 3);
    f32x4 s0 = *(const f32x4*)(sc + jx * 8), s1 = *(const f32x4*)(sc + jx * 8 + 4);
    f32x4 h0 = *(const f32x4*)(sh + jx * 8), h1 = *(const f32x4*)(sh + jx * 8 + 4);
    bf16x8 o;
#pragma unroll
    for (int e = 0; e < 4; ++e) {
      float a0 = fmaxf(fmaf(b2f((unsigned short)v[e]), s0[e], h0[e]), 0.f);
      float a1 = fmaxf(fmaf(b2f((unsigned short)v[e + 4]), s1[e], h1[e]), 0.f);
      o[e] = (short)f2b(pad ? 0.f : a0);
      o[e + 4] = (short)f2b(pad ? 0.f : a1);
    }
    *(bf16x8*)(Fs + ((r * 66 + p) << 8) + j * 16) = o;
  }
  if (t < 96) {
    int r = t >> 5, side = (t >> 4) & 1, jj = t & 15;
    int p = side ? 65 : 0;
    int jx = (jj & 8) | ((jj & 7) ^ (p & 7));
    int yy = y + r, xx = x0 + p;
    bf16x8 v = *(const bf16x8*)(src_base + (((b * PY + yy) * PX + xx) << 7) + jx * 8);
    bool pad = (yy == 0) | (yy == PY - 1) | (xx == 0) | (xx >= PX - 3);
    f32x4 s0 = *(const f32x4*)(sc + jx * 8), s1 = *(const f32x4*)(sc + jx * 8 + 4);
    f32x4 h0 = *(const f32x4*)(sh + jx * 8), h1 = *(const f32x4*)(sh + jx * 8 + 4);
    bf16x8 o;
#pragma unroll
    for (int e = 0; e < 4; ++e) {
      float a0 = fmaxf(fmaf(b2f((unsigned short)v[e]), s0[e], h0[e]), 0.f);
      float a1 = fmaxf(fmaf(b2f((unsigned short)v[e + 4]), s1[e], h1[e]), 0.f);
      o[e] = (short)f2b(pad ? 0.f : a0);
      o[e + 4] = (short)f2b(pad ? 0.f : a1);
    }
    *(bf16x8*)(Fs + ((r * 66 + p) << 8) + jj * 16) = o;
  }
}

// ---------------------------------------------------------------------------
// pac via MFMA: r12-verified config (4 waves, 2-tap ring, (256,2)) + setprio
// around the MFMA tap bodies (waves run unsynchronized after staging).
// ---------------------------------------------------------------------------
__global__ __launch_bounds__(256, 2) void pac_mfma(float* __restrict__ ws) {
  __shared__ __align__(16) char Fs[3 * 66 * 256];   // 50688 B
  int b, y, x0;
  decode_wg(blockIdx.x, b, y, x0);
  const int t = threadIdx.x;
  const unsigned short* Wtu = (const unsigned short*)(ws + WT_OFF);
  const unsigned short* fb = (const unsigned short*)(ws + FB_OFF);
  unsigned short* xnb = (unsigned short*)(ws + XNB_OFF);
  const int lane = t & 63, l15 = lane & 15, lg = lane >> 4;
  const int o0 = (t >> 6) * 32;

  const unsigned short* Wbase = Wtu + (o0 + l15) * 128 + lg * 8;   // +k*16384 +ot*2048 +ks*32
  const float* kernb = ws + KERN_OFF + ((b * 9) << 14) + (y << 7) + x0 + l15;

  // rings: wa[buf][ks*2+ot], kr[buf][pt]; prefetch distance 2 taps
  bf16x8 wa[3][8];
  float kr[3][4];
#pragma unroll
  for (int pk = 0; pk < 2; ++pk) {
#pragma unroll
    for (int ks = 0; ks < 4; ++ks) {
      wa[pk][ks * 2 + 0] = *(const bf16x8*)(Wbase + pk * 16384 + ks * 32);
      wa[pk][ks * 2 + 1] = *(const bf16x8*)(Wbase + pk * 16384 + 2048 + ks * 32);
    }
#pragma unroll
    for (int pt = 0; pt < 4; ++pt) kr[pk][pt] = kernb[(pk << 14) + pt * 16];
  }

  stage_tile(fb, Fs, b, y, x0, t);
  __syncthreads();

  const f32x4 vzero = {0.f, 0.f, 0.f, 0.f};
  f32x4 pacc0[4], pacc1[4];
#pragma unroll
  for (int pt = 0; pt < 4; ++pt) { pacc0[pt] = vzero; pacc1[pt] = vzero; }

#pragma unroll
  for (int k = 0; k < 9; ++k) {
    const int dy = k / 3, dxi = k % 3;        // compile-time under full unroll
    const int cur = k % 3;                    // compile-time
    // prefetch tap k+2 (A-frags + kern) into buf (k+2)%3
    if (k + 2 <= 8) {
      const int nb = (k + 2) % 3;
#pragma unroll
      for (int ks = 0; ks < 4; ++ks) {
        wa[nb][ks * 2 + 0] = *(const bf16x8*)(Wbase + (k + 2) * 16384 + ks * 32);
        wa[nb][ks * 2 + 1] = *(const bf16x8*)(Wbase + (k + 2) * 16384 + 2048 + ks * 32);
      }
#pragma unroll
      for (int pt = 0; pt < 4; ++pt) kr[nb][pt] = kernb[((k + 2) << 14) + pt * 16];
    }
    f32x4 z0[4], z1[4];
    __builtin_amdgcn_s_setprio(1);
#pragma unroll
    for (int ks = 0; ks < 4; ++ks) {
#pragma unroll
      for (int pt = 0; pt < 4; ++pt) {
        int p = dxi + pt * 16 + l15;
        int byte = ((dy * 66 + p) << 8) + ks * 64 + lg * 16;
        byte ^= (p & 7) << 4;
        bf16x8 bv = *(const bf16x8*)(Fs + byte);
        z0[pt] = MFMA16(wa[cur][ks * 2 + 0], bv, ks ? z0[pt] : vzero, 0, 0, 0);
        z1[pt] = MFMA16(wa[cur][ks * 2 + 1], bv, ks ? z1[pt] : vzero, 0, 0, 0);
      }
    }
    __builtin_amdgcn_s_setprio(0);
#pragma unroll
    for (int pt = 0; pt < 4; ++pt) {
      float kvv = kr[cur][pt];
#pragma unroll
      for (int i = 0; i < 4; ++i) {
        pacc0[pt][i] = fmaf(kvv, z0[pt][i], pacc0[pt][i]);
        pacc1[pt][i] = fmaf(kvv, z1[pt][i], pacc1[pt][i]);
      }
    }
  }

  // write raw bf16 pac (padded c-last) + stats from f32 accs
  float* sum1 = ws + SUM1;
  float* sumsq1 = ws + SUMSQ1;
#pragma unroll
  for (int pt = 0; pt < 4; ++pt) {
    int px = x0 + pt * 16 + l15;
    int base = ((b * PY + y + 1) * PX + px + 1) * 128;
    bf16x4 vA, vB;
#pragma unroll
    for (int i = 0; i < 4; ++i) { vA[i] = (short)f2b(pacc0[pt][i]); vB[i] = (short)f2b(pacc1[pt][i]); }
    *(bf16x4*)(xnb + base + o0 + lg * 4) = vA;
    *(bf16x4*)(xnb + base + o0 + 16 + lg * 4) = vB;
  }
#pragma unroll
  for (int half = 0; half < 2; ++half) {
#pragma unroll
    for (int i = 0; i < 4; ++i) {
      float s = 0.f, sq = 0.f;
#pragma unroll
      for (int pt = 0; pt < 4; ++pt) {
        float v = half ? pacc1[pt][i] : pacc0[pt][i];
        s += v; sq += v * v;
      }
#pragma unroll
      for (int m = 1; m < 16; m <<= 1) {
        s += __shfl_xor(s, m);
        sq += __shfl_xor(sq, m);
      }
      if (l15 == 0) {
        int o = o0 + half * 16 + lg * 4 + i;
        atomicAdd(&sum1[b * CIN + o], s);
        atomicAdd(&sumsq1[b * CIN + o], sq);
      }
    }
  }
}

// ---------------------------------------------------------------------------
// per-(b,c) stats -> scale = rsqrt(var+eps), shift = -mu*scale
// ---------------------------------------------------------------------------
__global__ void stats_kernel(float* __restrict__ ws, int sumoff, int sqoff,
                             int scoff, int shoff, int n, float invN) {
  int i = blockIdx.x * blockDim.x + threadIdx.x;
  if (i >= n) return;
  float mu = ws[sumoff + i] * invN;
  float var = ws[sqoff + i] * invN - mu * mu;
  var = fmaxf(var, 0.f);
  float rs = rsqrtf(var + EPS);
  ws[scoff + i] = rs;
  ws[shoff + i] = -mu * rs;
}

// ---------------------------------------------------------------------------
// decode conv via MFMA: r12 structure + fused IN1+ReLU staging + setprio.
// ---------------------------------------------------------------------------
__global__ __launch_bounds__(256, 3) void conv_mfma(float* __restrict__ ws,
                                                    float* __restrict__ out) {
  __shared__ __align__(16) char Xs[3 * 66 * 256];
  int b, y, x0;
  decode_wg(blockIdx.x, b, y, x0);
  const int t = threadIdx.x;
  const unsigned short* Ctu = (const unsigned short*)(ws + CT_OFF);
  const unsigned short* xnb = (const unsigned short*)(ws + XNB_OFF);
  const float* sc1 = ws + SCALE1 + b * CIN;
  const float* sh1 = ws + SHIFT1 + b * CIN;
  const int lane = t & 63, l15 = lane & 15, lg = lane >> 4;
  const int o0 = (t >> 6) * 16;

  const unsigned short* Cbase = Ctu + (o0 + l15) * 128 + lg * 8;   // +k*8192 +ks*32

  bf16x8 wa[3][4];
#pragma unroll
  for (int pk = 0; pk < 2; ++pk)
#pragma unroll
    for (int ks = 0; ks < 4; ++ks)
      wa[pk][ks] = *(const bf16x8*)(Cbase + pk * 8192 + ks * 32);

  stage_fused(xnb, Xs, sc1, sh1, b, y, x0, t);
  __syncthreads();

  const f32x4 vzero = {0.f, 0.f, 0.f, 0.f};
  f32x4 acc[4];
#pragma unroll
  for (int pt = 0; pt < 4; ++pt) acc[pt] = vzero;

#pragma unroll
  for (int k = 0; k < 9; ++k) {
    const int dy = k / 3, dxi = k % 3;
    const int cur = k % 3;
    if (k + 2 <= 8) {
      const int nb = (k + 2) % 3;
#pragma unroll
      for (int ks = 0; ks < 4; ++ks)
        wa[nb][ks] = *(const bf16x8*)(Cbase + (k + 2) * 8192 + ks * 32);
    }
    __builtin_amdgcn_s_setprio(1);
#pragma unroll
    for (int ks = 0; ks < 4; ++ks) {
#pragma unroll
      for (int pt = 0; pt < 4; ++pt) {
        int p = dxi + pt * 16 + l15;
        int byte = ((dy * 66 + p) << 8) + ks * 64 + lg * 16;
        byte ^= (p & 7) << 4;
        bf16x8 bv = *(const bf16x8*)(Xs + byte);
        acc[pt] = MFMA16(wa[cur][ks], bv, acc[pt], 0, 0, 0);
      }
    }
    __builtin_amdgcn_s_setprio(0);
  }

  float* sum2 = ws + SUM2;
  float* sumsq2 = ws + SUMSQ2;
#pragma unroll
  for (int pt = 0; pt < 4; ++pt) {
#pragma unroll
    for (int i = 0; i < 4; ++i) {
      int o = o0 + lg * 4 + i;
      int px = x0 + pt * 16 + l15;
      out[((b * COUT + o) << 14) + (y << 7) + px] = acc[pt][i];
    }
  }
#pragma unroll
  for (int i = 0; i < 4; ++i) {
    float s = 0.f, sq = 0.f;
#pragma unroll
    for (int pt = 0; pt < 4; ++pt) { float v = acc[pt][i]; s += v; sq += v * v; }
#pragma unroll
    for (int m = 1; m < 16; m <<= 1) {
      s += __shfl_xor(s, m);
      sq += __shfl_xor(sq, m);
    }
    if (l15 == 0) {
      int o = o0 + lg * 4 + i;
      atomicAdd(&sum2[b * COUT + o], s);
      atomicAdd(&sumsq2[b * COUT + o], sq);
    }
  }
}

// ---------------------------------------------------------------------------
// final InstanceNorm + ReLU on d_out (float4)
// ---------------------------------------------------------------------------
__global__ __launch_bounds__(256) void norm_kernel(float* __restrict__ out,
                                                   const float* __restrict__ ws) {
  int i = blockIdx.x * 256 + threadIdx.x;
  int bc = (i * 4) >> 14;
  float sc = ws[SCALE2 + bc];
  float sh = ws[SHIFT2 + bc];
  float4 v = reinterpret_cast<float4*>(out)[i];
  v.x = fmaxf(fmaf(v.x, sc, sh), 0.f);
  v.y = fmaxf(fmaf(v.y, sc, sh), 0.f);
  v.z = fmaxf(fmaf(v.z, sc, sh), 0.f);
  v.w = fmaxf(fmaf(v.w, sc, sh), 0.f);
  reinterpret_cast<float4*>(out)[i] = v;
}

extern "C" void kernel_launch(void* const* d_in, const int* in_sizes, int n_in,
                              void* d_out, int out_size, void* d_ws, size_t ws_size,
                              hipStream_t stream) {
  const float* feat = (const float*)d_in[0];
  const float* guide = (const float*)d_in[1];
  const float* pac_w = (const float*)d_in[2];
  const float* conv_w = (const float*)d_in[4];
  float* ws = (float*)d_ws;
  float* out = (float*)d_out;

  hipMemsetAsync(ws + STATS_OFF, 0, 1536 * sizeof(float), stream);

  prep_all<<<dim3(2594), 256, 0, stream>>>(feat, guide, pac_w, conv_w, ws);
  expk<<<dim3(576), 256, 0, stream>>>(ws);                   // consumes KPART -> kern
  pac_mfma<<<dim3(1024), 256, 0, stream>>>(ws);
  stats_kernel<<<dim3(2), 256, 0, stream>>>(ws, SUM1, SUMSQ1, SCALE1, SHIFT1,
                                            BATCH * CIN, 1.f / HW);
  conv_mfma<<<dim3(1024), 256, 0, stream>>>(ws, out);        // IN1+ReLU fused in stage
  stats_kernel<<<dim3(1), 256, 0, stream>>>(ws, SUM2, SUMSQ2, SCALE2, SHIFT2,
                                            BATCH * COUT, 1.f / HW);
  norm_kernel<<<dim3(BATCH * COUT * HW / 1024), 256, 0, stream>>>(out, ws);
}

// Round 15
// 151.084 us; speedup vs baseline: 1.4181x; 1.0418x over previous
//
#include <hip/hip_runtime.h>

#define H 128
#define W 128
#define HW 16384
#define CIN 128
#define COUT 64
#define BATCH 4
#define EPS 1e-5f
#define PY 130   // padded y extent
#define PX 132   // padded x extent

// ---- ws layout (float offsets) ----
// fb / xnb: bf16 [B][PY][PX][128] channels-last (fb pads zeroed; xnb pads unused/masked)
#define FB_OFF    0                    // 8785920 bf16 = 4392960 f32
#define XNB_OFF   4392960              // 8785920 bf16 = 4392960 f32
#define KPART_OFF XNB_OFF              // f32 [4][B][9][HW] TRANSIENT (consumed by expk before pac writes xnb)
#define KERN_OFF  (XNB_OFF + 4392960)  // 8785920: f32 [B][9][HW] = 589824
#define WT_OFF    (KERN_OFF + 589824)  // 9375744: bf16 [9][128][128] = 73728 f32
#define CT_OFF    (WT_OFF + 73728)     // 9449472: bf16 [9][64][128]  = 36864 f32
#define STATS_OFF (CT_OFF + 36864)     // 9486336
#define SUM1   (STATS_OFF)
#define SUMSQ1 (STATS_OFF + 512)
#define SUM2   (STATS_OFF + 1024)
#define SUMSQ2 (STATS_OFF + 1280)
#define SCALE1 (STATS_OFF + 1536)
#define SHIFT1 (STATS_OFF + 2048)
#define SCALE2 (STATS_OFF + 2560)
#define SHIFT2 (STATS_OFF + 2816)
// total 9489408 f32 = 38.0 MB

typedef float f32x4 __attribute__((ext_vector_type(4)));
typedef short bf16x8 __attribute__((ext_vector_type(8)));
typedef short bf16x4 __attribute__((ext_vector_type(4)));
#define MFMA16 __builtin_amdgcn_mfma_f32_16x16x32_bf16

__device__ __forceinline__ unsigned short f2b(float f) {
  union { float f; unsigned u; } un; un.f = f;
  unsigned r = un.u + 0x7FFF + ((un.u >> 16) & 1);   // RNE
  return (unsigned short)(r >> 16);
}
__device__ __forceinline__ float b2f(unsigned short u) {
  union { unsigned u; float f; } x; x.u = ((unsigned)u) << 16; return x.f;
}
__device__ __forceinline__ void load_lds16(const void* g, void* l) {
  __builtin_amdgcn_global_load_lds(
      (const __attribute__((address_space(1))) unsigned int*)g,
      (__attribute__((address_space(3))) unsigned int*)l, 16, 0, 0);
}

// XCD-chunked bijective swizzle for nwg=1024 (8 XCDs, 128 wgs per XCD chunk)
__device__ __forceinline__ void decode_wg(int bid, int& b, int& y, int& x0) {
  int wgid = (bid & 7) * 128 + (bid >> 3);
  b = wgid >> 8;
  int rem = wgid & 255;
  y = rem >> 1;
  x0 = (rem & 1) << 6;
}

// ---------------------------------------------------------------------------
// prep_all: ONE dispatch for 4 independent preprocessing jobs:
//   blocks [0,512):      transpose feat -> fb (channels-last bf16)
//   blocks [512,706):    zero fb pads
//   blocks [706,1570):   weight transform Wt / Ct
//   blocks [1570,2594):  kern partials kpart[cs][b][k][pix]
// ---------------------------------------------------------------------------
__global__ __launch_bounds__(256) void prep_all(const float* __restrict__ feat,
                                                const float* __restrict__ guide,
                                                const float* __restrict__ pw,
                                                const float* __restrict__ cw,
                                                float* __restrict__ ws) {
  __shared__ __align__(16) char T[128 * 256];   // used by transpose branch only
  const int bid = blockIdx.x;
  const int t = threadIdx.x;

  if (bid < 512) {
    // ---- transpose feat [b][c][y][x] f32 -> fb [b][y+1][x+1][c] bf16 ----
    int b = bid >> 7, y = bid & 127;
    int x = t & 127, ch = t >> 7;
    const float* fp = feat + ((b * CIN) << 14) + (y << 7) + x;
#pragma unroll 8
    for (int cc = 0; cc < 64; ++cc) {
      int c = ch * 64 + cc;
      float v = fp[c << 14];
      int byte = (x << 8) + (c << 1);
      byte ^= (x & 7) << 4;
      *(unsigned short*)(T + byte) = f2b(v);
    }
    __syncthreads();
    unsigned short* fb = (unsigned short*)(ws + FB_OFF);
#pragma unroll
    for (int it = 0; it < 8; ++it) {
      int flat = it * 256 + t;
      int px = flat >> 4, j = flat & 15;
      int byte = (px << 8) + (j << 4);
      byte ^= (px & 7) << 4;
      bf16x8 v = *(bf16x8*)(T + byte);
      *(bf16x8*)(fb + ((b * PY + y + 1) * PX + px + 1) * 128 + j * 8) = v;
    }
  } else if (bid < 706) {
    // ---- zero fb pads ----
    int id = (bid - 512) * 256 + t;
    if (id < 4 * 776 * 16) {
      int chunk = id & 15; int rest = id >> 4;
      int px = rest % 776; int b = rest / 776;
      int row, xx;
      if (px < 264) { row = (px < 132) ? 0 : 129; xx = px % 132; }
      else { int q = px - 264; row = 1 + (q >> 2); int m = q & 3; xx = m ? 128 + m : 0; }
      unsigned short* base = (unsigned short*)(ws + FB_OFF);
      bf16x8 z = {0, 0, 0, 0, 0, 0, 0, 0};
      *(bf16x8*)(base + ((b * PY + row) * PX + xx) * 128 + chunk * 8) = z;
    }
  } else if (bid < 1570) {
    // ---- weight transform ----
    int tg = (bid - 706) * 256 + t;
    unsigned short* Wtu = (unsigned short*)(ws + WT_OFF);
    unsigned short* Ctu = (unsigned short*)(ws + CT_OFF);
    if (tg < 147456) {
      int k = tg >> 14, rem = tg & 16383, o = rem >> 7, c = rem & 127;
      Wtu[tg] = f2b(pw[(o * CIN + c) * 9 + k]);
    } else {
      int u = tg - 147456;
      int k = u >> 13, rem = u & 8191, o = rem >> 7, c = rem & 127;
      Ctu[u] = f2b(cw[(o * CIN + c) * 9 + k]);
    }
  } else {
    // ---- kern partials: kpart[cs][b][k][pix] (c-loop unrolled 4x for MLP) ----
    int rel = bid - 1570;                  // 0..1023
    int cs = rel >> 8;
    int p = (rel & 255) * 256 + t;
    int b = p >> 14;
    int pix = p & (HW - 1);
    int y = pix >> 7, x = pix & (W - 1);
    float acc[9];
#pragma unroll
    for (int k = 0; k < 9; ++k) acc[k] = 0.f;
    const float* gb = guide + ((b * CIN + cs * 32) << 14);
#pragma unroll 4
    for (int c = 0; c < 32; ++c) {
      const float* gc = gb + (c << 14);
      float g0 = gc[pix];
#pragma unroll
      for (int dy = -1; dy <= 1; ++dy) {
#pragma unroll
        for (int dx = -1; dx <= 1; ++dx) {
          int yy = y + dy, xx = x + dx;
          bool ok = ((unsigned)yy < (unsigned)H) && ((unsigned)xx < (unsigned)W);
          int yc = min(max(yy, 0), H - 1);
          int xc = min(max(xx, 0), W - 1);
          float g = gc[yc * W + xc];
          g = ok ? g : 0.f;
          float d = g - g0;
          acc[(dy + 1) * 3 + (dx + 1)] += d * d;
        }
      }
    }
    float* kp = ws + KPART_OFF;
#pragma unroll
    for (int k = 0; k < 9; ++k)
      kp[(((cs * BATCH + b) * 9 + k) << 14) + pix] = acc[k];
  }
}

// kern = exp(-0.5 * sum_cs kpart)
__global__ __launch_bounds__(256) void expk(float* __restrict__ ws) {
  int i = blockIdx.x * 256 + threadIdx.x;   // float4 index, 147456 total
  const float4* kp = reinterpret_cast<const float4*>(ws + KPART_OFF);
  float4 a = kp[i], b = kp[i + 147456], c = kp[i + 2 * 147456], d = kp[i + 3 * 147456];
  float4 o;
  o.x = __expf(-0.5f * (a.x + b.x + c.x + d.x));
  o.y = __expf(-0.5f * (a.y + b.y + c.y + d.y));
  o.z = __expf(-0.5f * (a.z + b.z + c.z + d.z));
  o.w = __expf(-0.5f * (a.w + b.w + c.w + d.w));
  reinterpret_cast<float4*>(ws + KERN_OFF)[i] = o;
}

// ---------------------------------------------------------------------------
// pac tile stage (DMA): [3 rows][66 px][128 c] bf16, linear LDS, src pre-swizzled
// ---------------------------------------------------------------------------
__device__ __forceinline__ void stage_tile(const unsigned short* __restrict__ src_base,
                                           char* Fs, int b, int y, int x0, int t) {
  int lane = t & 63, w = t >> 6;
  int j = lane & 15, pl = lane >> 4;
#pragma unroll
  for (int q = 0; q < 12; ++q) {
    int m = w * 12 + q;
    int r = m >> 4, pblk = m & 15;
    int p = 1 + pblk * 4 + pl;
    int jx = (j & 8) | ((j & 7) ^ (p & 7));
    const unsigned short* src = src_base + (((b * PY + y + r) * PX + x0 + p) << 7) + jx * 8;
    char* dst = Fs + ((r * 66 + 1 + pblk * 4) << 8);
    load_lds16(src, dst);
  }
  if (t < 96) {
    int r = t >> 5, side = (t >> 4) & 1, jj = t & 15;
    int p = side ? 65 : 0;
    int jx = (jj & 8) | ((jj & 7) ^ (p & 7));
    const unsigned short* src = src_base + (((b * PY + y + r) * PX + x0 + p) << 7) + jx * 8;
    bf16x8 v = *(const bf16x8*)src;
    *(bf16x8*)(Fs + ((r * 66 + p) << 8) + jj * 16) = v;
  }
}

// ---------------------------------------------------------------------------
// conv tile stage (REGISTER path, fused IN1+ReLU+pad-mask)
// ---------------------------------------------------------------------------
__device__ __forceinline__ void stage_fused(const unsigned short* __restrict__ src_base,
                                            char* Fs, const float* __restrict__ sc,
                                            const float* __restrict__ sh,
                                            int b, int y, int x0, int t) {
  int lane = t & 63, w = t >> 6;
  int j = lane & 15, pl = lane >> 4;
#pragma unroll
  for (int q = 0; q < 12; ++q) {
    int m = w * 12 + q;
    int r = m >> 4, pblk = m & 15;
    int p = 1 + pblk * 4 + pl;
    int jx = (j & 8) | ((j & 7) ^ (p & 7));
    int yy = y + r, xx = x0 + p;
    bf16x8 v = *(const bf16x8*)(src_base + (((b * PY + yy) * PX + xx) << 7) + jx * 8);
    bool pad = (yy == 0) | (yy == PY - 1) | (xx == 0) | (xx >= PX - 3);
    f32x4 s0 = *(const f32x4*)(sc + jx * 8), s1 = *(const f32x4*)(sc + jx * 8 + 4);
    f32x4 h0 = *(const f32x4*)(sh + jx * 8), h1 = *(const f32x4*)(sh + jx * 8 + 4);
    bf16x8 o;
#pragma unroll
    for (int e = 0; e < 4; ++e) {
      float a0 = fmaxf(fmaf(b2f((unsigned short)v[e]), s0[e], h0[e]), 0.f);
      float a1 = fmaxf(fmaf(b2f((unsigned short)v[e + 4]), s1[e], h1[e]), 0.f);
      o[e] = (short)f2b(pad ? 0.f : a0);
      o[e + 4] = (short)f2b(pad ? 0.f : a1);
    }
    *(bf16x8*)(Fs + ((r * 66 + p) << 8) + j * 16) = o;
  }
  if (t < 96) {
    int r = t >> 5, side = (t >> 4) & 1, jj = t & 15;
    int p = side ? 65 : 0;
    int jx = (jj & 8) | ((jj & 7) ^ (p & 7));
    int yy = y + r, xx = x0 + p;
    bf16x8 v = *(const bf16x8*)(src_base + (((b * PY + yy) * PX + xx) << 7) + jx * 8);
    bool pad = (yy == 0) | (yy == PY - 1) | (xx == 0) | (xx >= PX - 3);
    f32x4 s0 = *(const f32x4*)(sc + jx * 8), s1 = *(const f32x4*)(sc + jx * 8 + 4);
    f32x4 h0 = *(const f32x4*)(sh + jx * 8), h1 = *(const f32x4*)(sh + jx * 8 + 4);
    bf16x8 o;
#pragma unroll
    for (int e = 0; e < 4; ++e) {
      float a0 = fmaxf(fmaf(b2f((unsigned short)v[e]), s0[e], h0[e]), 0.f);
      float a1 = fmaxf(fmaf(b2f((unsigned short)v[e + 4]), s1[e], h1[e]), 0.f);
      o[e] = (short)f2b(pad ? 0.f : a0);
      o[e + 4] = (short)f2b(pad ? 0.f : a1);
    }
    *(bf16x8*)(Fs + ((r * 66 + p) << 8) + jj * 16) = o;
  }
}

// ---------------------------------------------------------------------------
// pac via MFMA: r12-verified config (4 waves, 3-buf 2-tap ring, (256,2)).
// NO setprio (r14 showed it breaks the L2 write equilibrium: WRITE 33->82MB).
// ---------------------------------------------------------------------------
__global__ __launch_bounds__(256, 2) void pac_mfma(float* __restrict__ ws) {
  __shared__ __align__(16) char Fs[3 * 66 * 256];   // 50688 B
  int b, y, x0;
  decode_wg(blockIdx.x, b, y, x0);
  const int t = threadIdx.x;
  const unsigned short* Wtu = (const unsigned short*)(ws + WT_OFF);
  const unsigned short* fb = (const unsigned short*)(ws + FB_OFF);
  unsigned short* xnb = (unsigned short*)(ws + XNB_OFF);
  const int lane = t & 63, l15 = lane & 15, lg = lane >> 4;
  const int o0 = (t >> 6) * 32;

  const unsigned short* Wbase = Wtu + (o0 + l15) * 128 + lg * 8;   // +k*16384 +ot*2048 +ks*32
  const float* kernb = ws + KERN_OFF + ((b * 9) << 14) + (y << 7) + x0 + l15;

  // rings: wa[buf][ks*2+ot], kr[buf][pt]; prefetch distance 2 taps
  bf16x8 wa[3][8];
  float kr[3][4];
#pragma unroll
  for (int pk = 0; pk < 2; ++pk) {
#pragma unroll
    for (int ks = 0; ks < 4; ++ks) {
      wa[pk][ks * 2 + 0] = *(const bf16x8*)(Wbase + pk * 16384 + ks * 32);
      wa[pk][ks * 2 + 1] = *(const bf16x8*)(Wbase + pk * 16384 + 2048 + ks * 32);
    }
#pragma unroll
    for (int pt = 0; pt < 4; ++pt) kr[pk][pt] = kernb[(pk << 14) + pt * 16];
  }

  stage_tile(fb, Fs, b, y, x0, t);
  __syncthreads();

  const f32x4 vzero = {0.f, 0.f, 0.f, 0.f};
  f32x4 pacc0[4], pacc1[4];
#pragma unroll
  for (int pt = 0; pt < 4; ++pt) { pacc0[pt] = vzero; pacc1[pt] = vzero; }

#pragma unroll
  for (int k = 0; k < 9; ++k) {
    const int dy = k / 3, dxi = k % 3;        // compile-time under full unroll
    const int cur = k % 3;                    // compile-time
    // prefetch tap k+2 (A-frags + kern) into buf (k+2)%3
    if (k + 2 <= 8) {
      const int nb = (k + 2) % 3;
#pragma unroll
      for (int ks = 0; ks < 4; ++ks) {
        wa[nb][ks * 2 + 0] = *(const bf16x8*)(Wbase + (k + 2) * 16384 + ks * 32);
        wa[nb][ks * 2 + 1] = *(const bf16x8*)(Wbase + (k + 2) * 16384 + 2048 + ks * 32);
      }
#pragma unroll
      for (int pt = 0; pt < 4; ++pt) kr[nb][pt] = kernb[((k + 2) << 14) + pt * 16];
    }
    f32x4 z0[4], z1[4];
#pragma unroll
    for (int ks = 0; ks < 4; ++ks) {
#pragma unroll
      for (int pt = 0; pt < 4; ++pt) {
        int p = dxi + pt * 16 + l15;
        int byte = ((dy * 66 + p) << 8) + ks * 64 + lg * 16;
        byte ^= (p & 7) << 4;
        bf16x8 bv = *(const bf16x8*)(Fs + byte);
        z0[pt] = MFMA16(wa[cur][ks * 2 + 0], bv, ks ? z0[pt] : vzero, 0, 0, 0);
        z1[pt] = MFMA16(wa[cur][ks * 2 + 1], bv, ks ? z1[pt] : vzero, 0, 0, 0);
      }
    }
#pragma unroll
    for (int pt = 0; pt < 4; ++pt) {
      float kvv = kr[cur][pt];
#pragma unroll
      for (int i = 0; i < 4; ++i) {
        pacc0[pt][i] = fmaf(kvv, z0[pt][i], pacc0[pt][i]);
        pacc1[pt][i] = fmaf(kvv, z1[pt][i], pacc1[pt][i]);
      }
    }
  }

  // write raw bf16 pac (padded c-last) + stats from f32 accs
  float* sum1 = ws + SUM1;
  float* sumsq1 = ws + SUMSQ1;
#pragma unroll
  for (int pt = 0; pt < 4; ++pt) {
    int px = x0 + pt * 16 + l15;
    int base = ((b * PY + y + 1) * PX + px + 1) * 128;
    bf16x4 vA, vB;
#pragma unroll
    for (int i = 0; i < 4; ++i) { vA[i] = (short)f2b(pacc0[pt][i]); vB[i] = (short)f2b(pacc1[pt][i]); }
    *(bf16x4*)(xnb + base + o0 + lg * 4) = vA;
    *(bf16x4*)(xnb + base + o0 + 16 + lg * 4) = vB;
  }
#pragma unroll
  for (int half = 0; half < 2; ++half) {
#pragma unroll
    for (int i = 0; i < 4; ++i) {
      float s = 0.f, sq = 0.f;
#pragma unroll
      for (int pt = 0; pt < 4; ++pt) {
        float v = half ? pacc1[pt][i] : pacc0[pt][i];
        s += v; sq += v * v;
      }
#pragma unroll
      for (int m = 1; m < 16; m <<= 1) {
        s += __shfl_xor(s, m);
        sq += __shfl_xor(sq, m);
      }
      if (l15 == 0) {
        int o = o0 + half * 16 + lg * 4 + i;
        atomicAdd(&sum1[b * CIN + o], s);
        atomicAdd(&sumsq1[b * CIN + o], sq);
      }
    }
  }
}

// ---------------------------------------------------------------------------
// per-(b,c) stats -> scale = rsqrt(var+eps), shift = -mu*scale
// ---------------------------------------------------------------------------
__global__ void stats_kernel(float* __restrict__ ws, int sumoff, int sqoff,
                             int scoff, int shoff, int n, float invN) {
  int i = blockIdx.x * blockDim.x + threadIdx.x;
  if (i >= n) return;
  float mu = ws[sumoff + i] * invN;
  float var = ws[sqoff + i] * invN - mu * mu;
  var = fmaxf(var, 0.f);
  float rs = rsqrtf(var + EPS);
  ws[scoff + i] = rs;
  ws[shoff + i] = -mu * rs;
}

// ---------------------------------------------------------------------------
// decode conv via MFMA: r12 structure + fused IN1+ReLU staging. NO setprio.
// ---------------------------------------------------------------------------
__global__ __launch_bounds__(256, 3) void conv_mfma(float* __restrict__ ws,
                                                    float* __restrict__ out) {
  __shared__ __align__(16) char Xs[3 * 66 * 256];
  int b, y, x0;
  decode_wg(blockIdx.x, b, y, x0);
  const int t = threadIdx.x;
  const unsigned short* Ctu = (const unsigned short*)(ws + CT_OFF);
  const unsigned short* xnb = (const unsigned short*)(ws + XNB_OFF);
  const float* sc1 = ws + SCALE1 + b * CIN;
  const float* sh1 = ws + SHIFT1 + b * CIN;
  const int lane = t & 63, l15 = lane & 15, lg = lane >> 4;
  const int o0 = (t >> 6) * 16;

  const unsigned short* Cbase = Ctu + (o0 + l15) * 128 + lg * 8;   // +k*8192 +ks*32

  bf16x8 wa[3][4];
#pragma unroll
  for (int pk = 0; pk < 2; ++pk)
#pragma unroll
    for (int ks = 0; ks < 4; ++ks)
      wa[pk][ks] = *(const bf16x8*)(Cbase + pk * 8192 + ks * 32);

  stage_fused(xnb, Xs, sc1, sh1, b, y, x0, t);
  __syncthreads();

  const f32x4 vzero = {0.f, 0.f, 0.f, 0.f};
  f32x4 acc[4];
#pragma unroll
  for (int pt = 0; pt < 4; ++pt) acc[pt] = vzero;

#pragma unroll
  for (int k = 0; k < 9; ++k) {
    const int dy = k / 3, dxi = k % 3;
    const int cur = k % 3;
    if (k + 2 <= 8) {
      const int nb = (k + 2) % 3;
#pragma unroll
      for (int ks = 0; ks < 4; ++ks)
        wa[nb][ks] = *(const bf16x8*)(Cbase + (k + 2) * 8192 + ks * 32);
    }
#pragma unroll
    for (int ks = 0; ks < 4; ++ks) {
#pragma unroll
      for (int pt = 0; pt < 4; ++pt) {
        int p = dxi + pt * 16 + l15;
        int byte = ((dy * 66 + p) << 8) + ks * 64 + lg * 16;
        byte ^= (p & 7) << 4;
        bf16x8 bv = *(const bf16x8*)(Xs + byte);
        acc[pt] = MFMA16(wa[cur][ks], bv, acc[pt], 0, 0, 0);
      }
    }
  }

  float* sum2 = ws + SUM2;
  float* sumsq2 = ws + SUMSQ2;
#pragma unroll
  for (int pt = 0; pt < 4; ++pt) {
#pragma unroll
    for (int i = 0; i < 4; ++i) {
      int o = o0 + lg * 4 + i;
      int px = x0 + pt * 16 + l15;
      out[((b * COUT + o) << 14) + (y << 7) + px] = acc[pt][i];
    }
  }
#pragma unroll
  for (int i = 0; i < 4; ++i) {
    float s = 0.f, sq = 0.f;
#pragma unroll
    for (int pt = 0; pt < 4; ++pt) { float v = acc[pt][i]; s += v; sq += v * v; }
#pragma unroll
    for (int m = 1; m < 16; m <<= 1) {
      s += __shfl_xor(s, m);
      sq += __shfl_xor(sq, m);
    }
    if (l15 == 0) {
      int o = o0 + lg * 4 + i;
      atomicAdd(&sum2[b * COUT + o], s);
      atomicAdd(&sumsq2[b * COUT + o], sq);
    }
  }
}

// ---------------------------------------------------------------------------
// final InstanceNorm + ReLU on d_out (float4)
// ---------------------------------------------------------------------------
__global__ __launch_bounds__(256) void norm_kernel(float* __restrict__ out,
                                                   const float* __restrict__ ws) {
  int i = blockIdx.x * 256 + threadIdx.x;
  int bc = (i * 4) >> 14;
  float sc = ws[SCALE2 + bc];
  float sh = ws[SHIFT2 + bc];
  float4 v = reinterpret_cast<float4*>(out)[i];
  v.x = fmaxf(fmaf(v.x, sc, sh), 0.f);
  v.y = fmaxf(fmaf(v.y, sc, sh), 0.f);
  v.z = fmaxf(fmaf(v.z, sc, sh), 0.f);
  v.w = fmaxf(fmaf(v.w, sc, sh), 0.f);
  reinterpret_cast<float4*>(out)[i] = v;
}

extern "C" void kernel_launch(void* const* d_in, const int* in_sizes, int n_in,
                              void* d_out, int out_size, void* d_ws, size_t ws_size,
                              hipStream_t stream) {
  const float* feat = (const float*)d_in[0];
  const float* guide = (const float*)d_in[1];
  const float* pac_w = (const float*)d_in[2];
  const float* conv_w = (const float*)d_in[4];
  float* ws = (float*)d_ws;
  float* out = (float*)d_out;

  hipMemsetAsync(ws + STATS_OFF, 0, 1536 * sizeof(float), stream);

  prep_all<<<dim3(2594), 256, 0, stream>>>(feat, guide, pac_w, conv_w, ws);
  expk<<<dim3(576), 256, 0, stream>>>(ws);                   // consumes KPART -> kern
  pac_mfma<<<dim3(1024), 256, 0, stream>>>(ws);
  stats_kernel<<<dim3(2), 256, 0, stream>>>(ws, SUM1, SUMSQ1, SCALE1, SHIFT1,
                                            BATCH * CIN, 1.f / HW);
  conv_mfma<<<dim3(1024), 256, 0, stream>>>(ws, out);        // IN1+ReLU fused in stage
  stats_kernel<<<dim3(1), 256, 0, stream>>>(ws, SUM2, SUMSQ2, SCALE2, SHIFT2,
                                            BATCH * COUT, 1.f / HW);
  norm_kernel<<<dim3(BATCH * COUT * HW / 1024), 256, 0, stream>>>(out, ws);
}